// Round 7
// baseline (2919.627 us; speedup 1.0000x reference)
//
#include <hip/hip_runtime.h>
#include <hip/hip_bf16.h>

#define NBLK 128
#define NTHR 256                 // 4 waves = 1 wave/SIMD -> 512-reg budget/wave (no spill)
#define MTILE 64
#define KPAD 552                 // abuf row stride (elements); 1104 B, 16B-aligned
#define CHELEM (17*8*512)        // packed elements per 16-col chunk = 69632
#define LSTRIDE (16*CHELEM)      // packed elements per LSTM = 1,114,112

typedef __attribute__((ext_vector_type(8))) short short8;
typedef __attribute__((ext_vector_type(4))) float floatx4;

__device__ inline unsigned short f2bf(float x){
    unsigned u = __float_as_uint(x);
    return (unsigned short)((u + 0x7fffu + ((u>>16)&1u)) >> 16);
}
__device__ inline float bf2f(unsigned short v){ return __uint_as_float(((unsigned)v)<<16); }
__device__ inline float ex2(float x){ return __builtin_amdgcn_exp2f(x); }
__device__ inline float rcpn(float d){            // rcp + 1 Newton step
    float r = __builtin_amdgcn_rcpf(d);
    return r * (2.f - d*r);
}
#define LOG2E 1.4426950408889634f
__device__ inline float sigf(float x){ return rcpn(1.f + ex2(-LOG2E*x)); }
__device__ inline float tanh_(float x){ return 2.f*rcpn(1.f + ex2(-2.f*LOG2E*x)) - 1.f; }

// Packed layout: BP[chunk(16)][kt(17)][nt(8)][lane(64)][8]
// element = B[k][n], n = (chunk*8+nt)*16 + (lane&15), k = kt*32 + (lane>>4)*8 + j
// packed n decode: ch=n>>7, gate=(n>>5)&3, u=n&31 -> orig row = gate*512 + ch*32 + u
// K rows: 0..511 = W_hh, 512..515 = W_ih, 516 = b_ih+b_hh, 517..543 = 0
__global__ void prepack(const float* __restrict__ Wih, const float* __restrict__ Whh,
                        const float* __restrict__ bih, const float* __restrict__ bhh,
                        unsigned short* __restrict__ dst)
{
    int f = blockIdx.x*256 + threadIdx.x;
    if (f >= LSTRIDE) return;
    int j    = f & 7;
    int lane = (f>>3) & 63;
    int nt   = (f>>9) & 7;
    int rem  = f >> 12;
    int kt   = rem % 17;
    int chunk= rem / 17;
    int n = (chunk*8 + nt)*16 + (lane&15);
    int k = kt*32 + ((lane>>4)<<3) + j;
    int ch = n>>7, g = (n>>5)&3, u = n&31;
    int row = g*512 + ch*32 + u;
    float v = 0.f;
    if (k < 512)       v = Whh[row*512 + k];
    else if (k < 516)  v = Wih[row*4 + (k-512)];
    else if (k == 516) v = bih[row] + bhh[row];
    dst[f] = f2bf(v);
}

__global__ __launch_bounds__(NTHR, 1)
void lstm_all(const float* __restrict__ speed, const float* __restrict__ pos,
              const unsigned short* __restrict__ wpack,
              unsigned short* __restrict__ csaveG,
              unsigned short* __restrict__ hsaveG,
              const float* __restrict__ wfc, const float* __restrict__ bfc,
              const float* __restrict__ wemb, const float* __restrict__ bemb,
              float* __restrict__ out)
{
    // Double-buffered: pass reads abuf[rb], writes h to abuf[wbuf] -> no RAW race,
    // one barrier per step.
    __shared__ __align__(16) unsigned short abuf[2][MTILE][KPAD];  // 141312 B
    __shared__ float smallw[1040];                                 // 4160 B
    __shared__ float partial2[4][64][2];                           // 2048 B

    const int tid  = threadIdx.x;
    const int lane = tid & 63;
    const int wv   = tid >> 6;          // 0..3; wave owns chunks 4*wv .. 4*wv+3
    const int row0 = blockIdx.x * MTILE;
    const int l15  = lane & 15;
    const int lq   = lane >> 4;
    const short8 z8 = (short8){0,0,0,0,0,0,0,0};

    // ---- init: zero both buffers, smallw; bias-one in both; x_speed[0] in buf0 ----
    {
        for (int i = tid; i < 2*MTILE*(KPAD/8); i += NTHR) {
            int b = i / (MTILE*(KPAD/8));
            int rmd = i % (MTILE*(KPAD/8));
            int m = rmd / (KPAD/8), c8 = (rmd % (KPAD/8))*8;
            *(short8*)&abuf[b][m][c8] = z8;
        }
        for (int i = tid; i < 1024; i += NTHR) smallw[i] = wfc[i];
        if (tid < 2) smallw[1024+tid] = bfc[tid];
        if (tid < 8) smallw[1026+tid] = wemb[tid];
        if (tid < 4) smallw[1034+tid] = bemb[tid];
    }
    __syncthreads();
    if (tid < 128) abuf[tid>>6][tid&63][516] = 0x3F80;   // bias-one bf16(1.0), both buffers
    {
        int m = tid>>2, f3 = tid&3;                      // all 256 threads
        abuf[0][m][512+f3] = f2bf(speed[((size_t)(row0+m)*16 + 0)*4 + f3]);
    }
    __syncthreads();

    float cc0[32], cc1[32], cc2[32], cc3[32];
    #pragma unroll
    for (int i = 0; i < 32; ++i) { cc0[i]=0.f; cc1[i]=0.f; cc2[i]=0.f; cc3[i]=0.f; }

    // One chunk-pass (128 gate-cols = 32 hidden units x 4 gates) of one LSTM
    // step for M=64 rows: acc[4][8] (AGPR-resident), single all-gate epilogue.
    // s is a literal at every call site; cc is a named array.
    auto pass = [&](int rb, int wbuf, const unsigned short* wl, int s, float (&cc)[32]) {
        const int chunk = 4*wv + s;
        const unsigned short* bp = wl + (size_t)chunk*CHELEM + lane*8;
        floatx4 acc[4][8];
        #pragma unroll
        for (int mf = 0; mf < 4; ++mf)
            #pragma unroll
            for (int nt = 0; nt < 8; ++nt) acc[mf][nt] = (floatx4){0.f,0.f,0.f,0.f};
        short8 bA[8], bB[8];
        #pragma unroll
        for (int nt = 0; nt < 8; ++nt) bA[nt] = *(const short8*)(bp + nt*512);
        #pragma unroll 1
        for (int kt = 0; kt < 16; kt += 2) {
            const unsigned short* p1 = bp + (kt+1)*4096;
            #pragma unroll
            for (int nt = 0; nt < 8; ++nt) bB[nt] = *(const short8*)(p1 + nt*512);
            short8 a0 = *(const short8*)&abuf[rb][l15     ][kt*32 + lq*8];
            short8 a1 = *(const short8*)&abuf[rb][16 + l15][kt*32 + lq*8];
            short8 a2 = *(const short8*)&abuf[rb][32 + l15][kt*32 + lq*8];
            short8 a3 = *(const short8*)&abuf[rb][48 + l15][kt*32 + lq*8];
            #pragma unroll
            for (int nt = 0; nt < 8; ++nt) {
                acc[0][nt] = __builtin_amdgcn_mfma_f32_16x16x32_bf16(a0, bA[nt], acc[0][nt], 0,0,0);
                acc[1][nt] = __builtin_amdgcn_mfma_f32_16x16x32_bf16(a1, bA[nt], acc[1][nt], 0,0,0);
                acc[2][nt] = __builtin_amdgcn_mfma_f32_16x16x32_bf16(a2, bA[nt], acc[2][nt], 0,0,0);
                acc[3][nt] = __builtin_amdgcn_mfma_f32_16x16x32_bf16(a3, bA[nt], acc[3][nt], 0,0,0);
            }
            const unsigned short* p2 = bp + (kt+2)*4096;
            #pragma unroll
            for (int nt = 0; nt < 8; ++nt) bA[nt] = *(const short8*)(p2 + nt*512);
            a0 = *(const short8*)&abuf[rb][l15     ][(kt+1)*32 + lq*8];
            a1 = *(const short8*)&abuf[rb][16 + l15][(kt+1)*32 + lq*8];
            a2 = *(const short8*)&abuf[rb][32 + l15][(kt+1)*32 + lq*8];
            a3 = *(const short8*)&abuf[rb][48 + l15][(kt+1)*32 + lq*8];
            #pragma unroll
            for (int nt = 0; nt < 8; ++nt) {
                acc[0][nt] = __builtin_amdgcn_mfma_f32_16x16x32_bf16(a0, bB[nt], acc[0][nt], 0,0,0);
                acc[1][nt] = __builtin_amdgcn_mfma_f32_16x16x32_bf16(a1, bB[nt], acc[1][nt], 0,0,0);
                acc[2][nt] = __builtin_amdgcn_mfma_f32_16x16x32_bf16(a2, bB[nt], acc[2][nt], 0,0,0);
                acc[3][nt] = __builtin_amdgcn_mfma_f32_16x16x32_bf16(a3, bB[nt], acc[3][nt], 0,0,0);
            }
        }
        {   // kt=16 tail: bA holds kt=16 (loaded during kt=14 iter). ALL accs use bA.
            short8 a0 = *(const short8*)&abuf[rb][l15     ][16*32 + lq*8];
            short8 a1 = *(const short8*)&abuf[rb][16 + l15][16*32 + lq*8];
            short8 a2 = *(const short8*)&abuf[rb][32 + l15][16*32 + lq*8];
            short8 a3 = *(const short8*)&abuf[rb][48 + l15][16*32 + lq*8];
            #pragma unroll
            for (int nt = 0; nt < 8; ++nt) {
                acc[0][nt] = __builtin_amdgcn_mfma_f32_16x16x32_bf16(a0, bA[nt], acc[0][nt], 0,0,0);
                acc[1][nt] = __builtin_amdgcn_mfma_f32_16x16x32_bf16(a1, bA[nt], acc[1][nt], 0,0,0);
                acc[2][nt] = __builtin_amdgcn_mfma_f32_16x16x32_bf16(a2, bA[nt], acc[2][nt], 0,0,0);
                acc[3][nt] = __builtin_amdgcn_mfma_f32_16x16x32_bf16(a3, bA[nt], acc[3][nt], 0,0,0);
            }
        }
        // ntile pairs: 0..1=i, 2..3=f, 4..5=g, 6..7=o (up = nt&1). Full cell update.
        #pragma unroll
        for (int mf = 0; mf < 4; ++mf)
            #pragma unroll
            for (int up = 0; up < 2; ++up)
                #pragma unroll
                for (int r = 0; r < 4; ++r) {
                    int idx = (mf*2+up)*4 + r;
                    float gi = acc[mf][0+up][r];
                    float gf = acc[mf][2+up][r];
                    float gg = acc[mf][4+up][r];
                    float go = acc[mf][6+up][r];
                    float cn = sigf(gf)*cc[idx] + sigf(gi)*tanh_(gg);
                    cc[idx] = cn;
                    float h = sigf(go)*tanh_(cn);
                    abuf[wbuf][mf*16 + lq*4 + r][chunk*32 + up*16 + l15] = f2bf(h);
                }
    };

    const unsigned short* wsp = wpack;
    const unsigned short* wpp = wpack + LSTRIDE;
    const unsigned short* wdp = wpack + 2*(size_t)LSTRIDE;
    unsigned short* hs_g = hsaveG + (size_t)blockIdx.x*MTILE*512;
    unsigned short* cs_g = csaveG + (size_t)blockIdx.x*MTILE*512;

    // ---- speed encoder ----
    #pragma unroll 1
    for (int t = 0; t < 16; ++t) {
        int rb = t&1, wbuf = (t+1)&1;
        pass(rb, wbuf, wsp, 0, cc0);
        pass(rb, wbuf, wsp, 1, cc1);
        pass(rb, wbuf, wsp, 2, cc2);
        pass(rb, wbuf, wsp, 3, cc3);
        if (t < 15) {
            int m = tid>>2, f3 = tid&3;
            abuf[wbuf][m][512+f3] = f2bf(speed[((size_t)(row0+m)*16 + t+1)*4 + f3]);
        }
        __syncthreads();
    }
    // ---- speed -> pos transition ----
    // final h_s is in abuf[0]; stage h_s -> global (coalesced short8)
    for (int i = tid; i < MTILE*64; i += NTHR) {
        int m = i>>6, cb = (i&63)*8;
        *(short8*)&hs_g[m*512 + cb] = *(const short8*)&abuf[0][m][cb];
    }
    {   // scatter c (bf16, MFMA layout) -> abuf[1] cols 0..511 (it is idle now)
        #pragma unroll
        for (int s = 0; s < 4; ++s)
            #pragma unroll
            for (int mf = 0; mf < 4; ++mf)
                #pragma unroll
                for (int up = 0; up < 2; ++up)
                    #pragma unroll
                    for (int r = 0; r < 4; ++r) {
                        int idx = (mf*2+up)*4 + r;
                        int m = mf*16 + lq*4 + r;
                        int u = (4*wv+s)*32 + up*16 + l15;
                        float v = (s==0) ? cc0[idx] : (s==1) ? cc1[idx] : (s==2) ? cc2[idx] : cc3[idx];
                        abuf[1][m][u] = f2bf(v);
                    }
    }
    __syncthreads();
    // abuf[1] c-staging -> global (coalesced); re-zero buf0 h; x_pos[0]; reset cc
    for (int i = tid; i < MTILE*64; i += NTHR) {
        int m = i>>6, cb = (i&63)*8;
        *(short8*)&cs_g[m*512 + cb] = *(const short8*)&abuf[1][m][cb];
        *(short8*)&abuf[0][m][cb] = z8;
    }
    {
        int m = tid>>2, f3 = tid&3;
        abuf[0][m][512+f3] = f2bf(pos[((size_t)(row0+m)*16 + 0)*4 + f3]);
    }
    #pragma unroll
    for (int i = 0; i < 32; ++i) { cc0[i]=0.f; cc1[i]=0.f; cc2[i]=0.f; cc3[i]=0.f; }
    __syncthreads();

    // ---- pos encoder ----
    #pragma unroll 1
    for (int t = 0; t < 16; ++t) {
        int rb = t&1, wbuf = (t+1)&1;
        pass(rb, wbuf, wpp, 0, cc0);
        pass(rb, wbuf, wpp, 1, cc1);
        pass(rb, wbuf, wpp, 2, cc2);
        pass(rb, wbuf, wpp, 3, cc3);
        if (t < 15) {
            int m = tid>>2, f3 = tid&3;
            abuf[wbuf][m][512+f3] = f2bf(pos[((size_t)(row0+m)*16 + t+1)*4 + f3]);
        }
        __syncthreads();
    }
    // ---- combine: h0 = h_p + h_s (in buf0); c += c_s; x = pos[:,15,:] ----
    for (int i = tid; i < MTILE*64; i += NTHR) {
        int m = i>>6, cb = (i&63)*8;
        *(short8*)&abuf[1][m][cb] = *(const short8*)&cs_g[m*512 + cb];  // c_s -> buf1 staging
        short8 hv = *(const short8*)&abuf[0][m][cb];
        short8 sv = *(const short8*)&hs_g[m*512 + cb];
        short8 o;
        #pragma unroll
        for (int q = 0; q < 8; ++q)
            o[q] = (short)f2bf(bf2f((unsigned short)hv[q]) + bf2f((unsigned short)sv[q]));
        *(short8*)&abuf[0][m][cb] = o;
    }
    {
        int m = tid>>2, f3 = tid&3;
        abuf[0][m][512+f3] = f2bf(pos[((size_t)(row0+m)*16 + 15)*4 + f3]);
    }
    __syncthreads();
    {   // c += c_s (scattered LDS reads from buf1 staging)
        #pragma unroll
        for (int s = 0; s < 4; ++s)
            #pragma unroll
            for (int mf = 0; mf < 4; ++mf)
                #pragma unroll
                for (int up = 0; up < 2; ++up)
                    #pragma unroll
                    for (int r = 0; r < 4; ++r) {
                        int idx = (mf*2+up)*4 + r;
                        int m = mf*16 + lq*4 + r;
                        int u = (4*wv+s)*32 + up*16 + l15;
                        float v = bf2f(abuf[1][m][u]);
                        if (s==0) cc0[idx] += v; else if (s==1) cc1[idx] += v;
                        else if (s==2) cc2[idx] += v; else cc3[idx] += v;
                    }
    }
    __syncthreads();   // all c-reads of buf1 done before decoder t=0 writes h into buf1

    // ---- decoder ----
    #pragma unroll 1
    for (int t = 0; t < 16; ++t) {
        int rb = t&1, wbuf = (t+1)&1;
        pass(rb, wbuf, wdp, 0, cc0);
        pass(rb, wbuf, wdp, 1, cc1);
        pass(rb, wbuf, wdp, 2, cc2);
        pass(rb, wbuf, wdp, 3, cc3);
        __syncthreads();
        {   // crossing partials: wave wv covers k-slice [wv*128, wv*128+128); lane = row
            int r = lane;
            float p0 = 0.f, p1 = 0.f;
            #pragma unroll
            for (int k = 0; k < 128; ++k) {
                float hv = bf2f(abuf[wbuf][r][wv*128 + k]);
                p0 += hv * smallw[       wv*128 + k];
                p1 += hv * smallw[512 +  wv*128 + k];
            }
            partial2[wv][r][0] = p0;
            partial2[wv][r][1] = p1;
        }
        __syncthreads();
        if (wv == 0) {
            int r = lane;
            float p0 = 0.f, p1 = 0.f;
            #pragma unroll
            for (int i = 0; i < 4; ++i) { p0 += partial2[i][r][0]; p1 += partial2[i][r][1]; }
            p0 += smallw[1024]; p1 += smallw[1025];
            float cr0 = fmaxf(p0, 0.f), cr1 = fmaxf(p1, 0.f);
            float mx = fmaxf(cr0, cr1);
            float e0 = ex2(LOG2E*(cr0-mx)), e1 = ex2(LOG2E*(cr1-mx));
            float inv = rcpn(e0+e1);
            out[((size_t)(row0+r))*32 + t*2 + 0] = e0*inv;
            out[((size_t)(row0+r))*32 + t*2 + 1] = e1*inv;
            #pragma unroll
            for (int e = 0; e < 4; ++e) {
                float lp = fmaxf(cr0*smallw[1026+e*2] + cr1*smallw[1026+e*2+1] + smallw[1034+e], 0.f);
                abuf[wbuf][r][512+e] = f2bf(lp);
            }
        }
        __syncthreads();
    }
}

extern "C" void kernel_launch(void* const* d_in, const int* in_sizes, int n_in,
                              void* d_out, int out_size, void* d_ws, size_t ws_size,
                              hipStream_t stream)
{
    (void)in_sizes; (void)n_in; (void)out_size; (void)ws_size;
    const float* speed = (const float*)d_in[0];
    const float* pos   = (const float*)d_in[1];
    const float* Ws_ih = (const float*)d_in[2];
    const float* Ws_hh = (const float*)d_in[3];
    const float* bs_ih = (const float*)d_in[4];
    const float* bs_hh = (const float*)d_in[5];
    const float* Wp_ih = (const float*)d_in[6];
    const float* Wp_hh = (const float*)d_in[7];
    const float* bp_ih = (const float*)d_in[8];
    const float* bp_hh = (const float*)d_in[9];
    const float* Wd_ih = (const float*)d_in[10];
    const float* Wd_hh = (const float*)d_in[11];
    const float* bd_ih = (const float*)d_in[12];
    const float* bd_hh = (const float*)d_in[13];
    const float* W_fc  = (const float*)d_in[14];
    const float* b_fc  = (const float*)d_in[15];
    const float* W_emb = (const float*)d_in[16];
    const float* b_emb = (const float*)d_in[17];

    unsigned short* wp = (unsigned short*)d_ws;
    unsigned short* csave = wp + 3*(size_t)LSTRIDE;                 // 8 MB
    unsigned short* hsave = csave + (size_t)NBLK*MTILE*512;         // 8 MB
    int gb = (LSTRIDE + 255) / 256;
    prepack<<<gb, 256, 0, stream>>>(Ws_ih, Ws_hh, bs_ih, bs_hh, wp);
    prepack<<<gb, 256, 0, stream>>>(Wp_ih, Wp_hh, bp_ih, bp_hh, wp + LSTRIDE);
    prepack<<<gb, 256, 0, stream>>>(Wd_ih, Wd_hh, bd_ih, bd_hh, wp + 2*(size_t)LSTRIDE);
    lstm_all<<<NBLK, NTHR, 0, stream>>>(speed, pos, wp, csave, hsave,
                                        W_fc, b_fc, W_emb, b_emb, (float*)d_out);
}

// Round 8
// 782.794 us; speedup vs baseline: 3.7298x; 3.7298x over previous
//
#include <hip/hip_runtime.h>

#define NBLK 256
#define NTHR 512
#define MTILE 32
#define KPADI 592                // abuf row stride bytes (16-aligned, 148 banks -> ~conflict-free)
#define HSTR  528                // hsave row stride bytes
#define CHB   (9*8*64*16)        // 73728 bytes per 16-col chunk per LSTM (9 k-tiles of K=64)
#define LSTR  (16*CHB)           // 1179648 bytes per LSTM

typedef __attribute__((ext_vector_type(4))) int int4v;

__device__ inline float ex2(float x){ return __builtin_amdgcn_exp2f(x); }
__device__ inline float rcpn(float d){ float r=__builtin_amdgcn_rcpf(d); return r*(2.f-d*r); }
#define LOG2E 1.4426950408889634f
__device__ inline float sigf(float x){ return rcpn(1.f+ex2(-LOG2E*x)); }
__device__ inline float tanh_(float x){ return 2.f*rcpn(1.f+ex2(-2.f*LOG2E*x))-1.f; }

// ---- per-LSTM scale: max(|Whh|, |Wih|, |bih+bhh|/2), via atomicMax on float bits.
// d_ws poison 0xAAAAAAAA is a negative int -> any |v|>=0 wins.
__global__ void scale_k(const float* Ws_ih, const float* Ws_hh, const float* bs_ih, const float* bs_hh,
                        const float* Wp_ih, const float* Wp_hh, const float* bp_ih, const float* bp_hh,
                        const float* Wd_ih, const float* Wd_hh, const float* bd_ih, const float* bd_hh,
                        int* smax)
{
    int L = blockIdx.x >> 5;
    int blk = blockIdx.x & 31;
    const float* Wih = L==0 ? Ws_ih : L==1 ? Wp_ih : Wd_ih;
    const float* Whh = L==0 ? Ws_hh : L==1 ? Wp_hh : Wd_hh;
    const float* bih = L==0 ? bs_ih : L==1 ? bp_ih : bd_ih;
    const float* bhh = L==0 ? bs_hh : L==1 ? bp_hh : bd_hh;
    float m = 0.f;
    for (int i = blk*256 + threadIdx.x; i < 2048*512; i += 32*256) m = fmaxf(m, fabsf(Whh[i]));
    for (int i = blk*256 + threadIdx.x; i < 2048*4;   i += 32*256) m = fmaxf(m, fabsf(Wih[i]));
    for (int i = blk*256 + threadIdx.x; i < 2048;     i += 32*256) m = fmaxf(m, 0.5f*fabsf(bih[i]+bhh[i]));
    __shared__ float red[256];
    red[threadIdx.x] = m; __syncthreads();
    for (int s = 128; s; s >>= 1){
        if (threadIdx.x < s) red[threadIdx.x] = fmaxf(red[threadIdx.x], red[threadIdx.x+s]);
        __syncthreads();
    }
    if (threadIdx.x == 0) atomicMax(&smax[L], __float_as_int(red[0]));
}

// Pack: BP[chunk(16)][kt(9)][nt(8)][lane(64)][16 i8]; element B[k][n]:
// n=(chunk*8+nt)*16+(lane&15), k=kt*64+(lane>>4)*16+j. Packed n decode: ch=n>>7,
// g=(n>>5)&3, u=n&31 -> row=g*512+ch*32+u. K rows: 0..511=Whh; 512..527=Wih
// x-replicas (A side holds x/4, 4 copies per dim); 528..529=(b_ih+b_hh)/2 (A side
// holds "one"=127); 530..575=0.
__global__ void pack_k(const float* Wih, const float* Whh, const float* bih, const float* bhh,
                       const int* smax, int L, unsigned char* dst, float* gsout)
{
    int f4 = blockIdx.x*256 + threadIdx.x;
    if (f4*4 >= LSTR) return;
    float mx = __int_as_float(smax[L]);
    float inv = 127.f / mx;                                  // 1/s_w
    if (blockIdx.x==0 && threadIdx.x==0) gsout[L] = mx * (1.f/(127.f*127.f)); // s_w*s_h
    int fb = f4*4;
    int lane=(fb>>4)&63, nt=(fb>>10)&7, t=fb>>13;
    int kt=t%9, chunk=t/9;
    int n = (chunk*8+nt)*16 + (lane&15);
    int ch=n>>7, g=(n>>5)&3, u=n&31;
    int row = g*512 + ch*32 + u;
    int kbase = kt*64 + ((lane>>4)<<4) + (fb&15);
    unsigned out = 0;
    #pragma unroll
    for (int b=0;b<4;++b){
        int k = kbase + b;
        float v = 0.f;
        if (k < 512)      v = Whh[row*512+k];
        else if (k < 528) v = Wih[row*4 + (k&3)];
        else if (k < 530) v = 0.5f*(bih[row]+bhh[row]);
        int q = (int)rintf(v*inv);
        q = q>127?127:(q<-127?-127:q);
        out |= ((unsigned)(q & 255)) << (8*b);
    }
    *(unsigned*)(dst + fb) = out;
}

__global__ __launch_bounds__(NTHR, 1)
void lstm_all(const float* __restrict__ speed, const float* __restrict__ pos,
              const unsigned char* __restrict__ wpack, const float* __restrict__ gsb,
              const float* __restrict__ wfc, const float* __restrict__ bfc,
              const float* __restrict__ wemb, const float* __restrict__ bemb,
              float* __restrict__ out)
{
    __shared__ __align__(16) unsigned char abuf[2][MTILE][KPADI];  // 37888 B
    __shared__ __align__(16) unsigned char hsave[MTILE][HSTR];     // 16896 B
    __shared__ float csave[MTILE][512];                            // 65536 B
    __shared__ float smallw[1040];                                 // 4160 B
    __shared__ float partial[NTHR];                                // 2048 B

    const int tid  = threadIdx.x;
    const int lane = tid & 63;
    const int wv   = tid >> 6;          // 0..7
    const int row0 = blockIdx.x * MTILE;
    const int l15  = lane & 15;
    const int lq   = lane >> 4;

    const float gs0 = gsb[0], gs1 = gsb[1], gs2 = gsb[2];

    // ---- init LDS: zero both abuf, ones rows, x_speed[0], smallw ----
    {
        for (int i = tid; i < 2*MTILE*(KPADI/16); i += NTHR) {
            int b = i / (MTILE*(KPADI/16));
            int rmd = i % (MTILE*(KPADI/16));
            int m = rmd / (KPADI/16), c16 = (rmd % (KPADI/16))*16;
            *(int4v*)&abuf[b][m][c16] = (int4v){0,0,0,0};
        }
        for (int i = tid; i < 1024; i += NTHR) smallw[i] = wfc[i];
        if (tid < 2) smallw[1024+tid] = bfc[tid];
        if (tid < 8) smallw[1026+tid] = wemb[tid];
        if (tid < 4) smallw[1034+tid] = bemb[tid];
    }
    __syncthreads();
    if (tid < 64) { int b = tid>>5, m = tid&31; abuf[b][m][528] = 127; abuf[b][m][529] = 127; }
    if (tid < 128) {
        int m = tid>>2, f3 = tid&3;
        float x = speed[((size_t)(row0+m)*16 + 0)*4 + f3];
        int q = (int)rintf(fminf(fmaxf(x*31.75f,-127.f),127.f));
        unsigned char qb = (unsigned char)q;
        abuf[0][m][512+f3]=qb; abuf[0][m][516+f3]=qb; abuf[0][m][520+f3]=qb; abuf[0][m][524+f3]=qb;
    }
    __syncthreads();

    float cc0[16], cc1[16];
    #pragma unroll
    for (int i = 0; i < 16; ++i) { cc0[i]=0.f; cc1[i]=0.f; }

    // One chunk-pass (128 gate-cols) of one cell step for M=32. s literal at all
    // call sites. DUAL: also accumulate W_hh * hsave (tiles 0..7). DEFER: return
    // h-bytes in hq instead of writing LDS (decoder t=0).
    auto pass = [&](int rb, int wbuf, const unsigned char* wl, int s, float (&cc)[16],
                    float gs, int DUAL, int DEFER, int (&hq)[16]) {
        const int chunk = 2*wv + s;
        const unsigned char* bp = wl + (size_t)chunk*CHB + lane*16;
        const unsigned char* ar0 = &abuf[rb][l15][0];
        const unsigned char* ar1 = &abuf[rb][16+l15][0];
        int4v acc[2][8];
        #pragma unroll
        for (int mf=0;mf<2;++mf)
            #pragma unroll
            for (int nt=0;nt<8;++nt) acc[mf][nt] = (int4v){0,0,0,0};
        int4v bA[8], bB[8];
        #pragma unroll
        for (int nt=0;nt<8;++nt) bA[nt] = *(const int4v*)(bp + nt*1024);
        #pragma unroll 1
        for (int kt=0; kt<8; kt+=2){
            const unsigned char* p1 = bp + (kt+1)*8192;
            #pragma unroll
            for (int nt=0;nt<8;++nt) bB[nt] = *(const int4v*)(p1 + nt*1024);
            int4v a0 = *(const int4v*)(ar0 + kt*64 + lq*16);
            int4v a1 = *(const int4v*)(ar1 + kt*64 + lq*16);
            #pragma unroll
            for (int nt=0;nt<8;++nt){
                acc[0][nt] = __builtin_amdgcn_mfma_i32_16x16x64_i8(a0, bA[nt], acc[0][nt], 0,0,0);
                acc[1][nt] = __builtin_amdgcn_mfma_i32_16x16x64_i8(a1, bA[nt], acc[1][nt], 0,0,0);
            }
            const unsigned char* p2 = bp + (kt+2)*8192;
            #pragma unroll
            for (int nt=0;nt<8;++nt) bA[nt] = *(const int4v*)(p2 + nt*1024);
            a0 = *(const int4v*)(ar0 + (kt+1)*64 + lq*16);
            a1 = *(const int4v*)(ar1 + (kt+1)*64 + lq*16);
            #pragma unroll
            for (int nt=0;nt<8;++nt){
                acc[0][nt] = __builtin_amdgcn_mfma_i32_16x16x64_i8(a0, bB[nt], acc[0][nt], 0,0,0);
                acc[1][nt] = __builtin_amdgcn_mfma_i32_16x16x64_i8(a1, bB[nt], acc[1][nt], 0,0,0);
            }
        }
        {   // kt=8 tail (x/bias tile): bA holds tile 8 (loaded during kt=6). ALL accs use bA.
            int4v a0 = *(const int4v*)(ar0 + 8*64 + lq*16);
            int4v a1 = *(const int4v*)(ar1 + 8*64 + lq*16);
            #pragma unroll
            for (int nt=0;nt<8;++nt){
                acc[0][nt] = __builtin_amdgcn_mfma_i32_16x16x64_i8(a0, bA[nt], acc[0][nt], 0,0,0);
                acc[1][nt] = __builtin_amdgcn_mfma_i32_16x16x64_i8(a1, bA[nt], acc[1][nt], 0,0,0);
            }
        }
        if (DUAL) {   // += W_hh * hsave, tiles 0..7 (even count: no tail)
            const unsigned char* hr0 = &hsave[l15][0];
            const unsigned char* hr1 = &hsave[16+l15][0];
            #pragma unroll
            for (int nt=0;nt<8;++nt) bA[nt] = *(const int4v*)(bp + nt*1024);
            #pragma unroll 1
            for (int kt=0; kt<8; kt+=2){
                const unsigned char* p1 = bp + (kt+1)*8192;
                #pragma unroll
                for (int nt=0;nt<8;++nt) bB[nt] = *(const int4v*)(p1 + nt*1024);
                int4v a0 = *(const int4v*)(hr0 + kt*64 + lq*16);
                int4v a1 = *(const int4v*)(hr1 + kt*64 + lq*16);
                #pragma unroll
                for (int nt=0;nt<8;++nt){
                    acc[0][nt] = __builtin_amdgcn_mfma_i32_16x16x64_i8(a0, bA[nt], acc[0][nt], 0,0,0);
                    acc[1][nt] = __builtin_amdgcn_mfma_i32_16x16x64_i8(a1, bA[nt], acc[1][nt], 0,0,0);
                }
                const unsigned char* p2 = bp + (kt+2)*8192;   // kt=6 loads tile 8: unused, harmless
                #pragma unroll
                for (int nt=0;nt<8;++nt) bA[nt] = *(const int4v*)(p2 + nt*1024);
                a0 = *(const int4v*)(hr0 + (kt+1)*64 + lq*16);
                a1 = *(const int4v*)(hr1 + (kt+1)*64 + lq*16);
                #pragma unroll
                for (int nt=0;nt<8;++nt){
                    acc[0][nt] = __builtin_amdgcn_mfma_i32_16x16x64_i8(a0, bB[nt], acc[0][nt], 0,0,0);
                    acc[1][nt] = __builtin_amdgcn_mfma_i32_16x16x64_i8(a1, bB[nt], acc[1][nt], 0,0,0);
                }
            }
        }
        // nt pairs: 0..1=i, 2..3=f, 4..5=g, 6..7=o (up=nt&1). gate = acc*gs.
        #pragma unroll
        for (int mf=0;mf<2;++mf)
            #pragma unroll
            for (int up=0;up<2;++up)
                #pragma unroll
                for (int r=0;r<4;++r){
                    int idx = (mf*2+up)*4 + r;
                    float gi = (float)acc[mf][0+up][r] * gs;
                    float gf = (float)acc[mf][2+up][r] * gs;
                    float gg = (float)acc[mf][4+up][r] * gs;
                    float go = (float)acc[mf][6+up][r] * gs;
                    float cn = sigf(gf)*cc[idx] + sigf(gi)*tanh_(gg);
                    cc[idx] = cn;
                    float h = sigf(go)*tanh_(cn);
                    int q = (int)rintf(h*127.f);
                    if (DEFER) hq[idx] = q;
                    else abuf[wbuf][mf*16+lq*4+r][chunk*32+up*16+l15] = (unsigned char)q;
                }
    };

    const unsigned char* wsp = wpack;
    const unsigned char* wpp = wpack + (size_t)LSTR;
    const unsigned char* wdp = wpack + 2*(size_t)LSTR;
    int dmy[16];

    // ---- speed encoder ----
    #pragma unroll 1
    for (int t=0;t<16;++t){
        int rb=t&1, wbuf=(t+1)&1;
        pass(rb,wbuf,wsp,0,cc0,gs0,0,0,dmy);
        pass(rb,wbuf,wsp,1,cc1,gs0,0,0,dmy);
        if (t<15 && tid<128){
            int m=tid>>2, f3=tid&3;
            float x = speed[((size_t)(row0+m)*16 + t+1)*4 + f3];
            int q = (int)rintf(fminf(fmaxf(x*31.75f,-127.f),127.f));
            unsigned char qb=(unsigned char)q;
            abuf[wbuf][m][512+f3]=qb; abuf[wbuf][m][516+f3]=qb; abuf[wbuf][m][520+f3]=qb; abuf[wbuf][m][524+f3]=qb;
        }
        __syncthreads();
    }
    // ---- speed -> pos transition (final h_s in abuf[0]) ----
    for (int i=tid; i<MTILE*32; i+=NTHR){          // 32 rows x 512 B in 16 B units
        int m=i>>5, cb=(i&31)*16;
        *(int4v*)&hsave[m][cb] = *(const int4v*)&abuf[0][m][cb];
        *(int4v*)&abuf[0][m][cb] = (int4v){0,0,0,0};
    }
    #pragma unroll
    for (int s2=0;s2<2;++s2)
        #pragma unroll
        for (int mf=0;mf<2;++mf)
            #pragma unroll
            for (int up=0;up<2;++up)
                #pragma unroll
                for (int r=0;r<4;++r){
                    int idx=(mf*2+up)*4+r;
                    csave[mf*16+lq*4+r][(2*wv+s2)*32+up*16+l15] = s2 ? cc1[idx] : cc0[idx];
                }
    #pragma unroll
    for (int i=0;i<16;++i){ cc0[i]=0.f; cc1[i]=0.f; }
    if (tid < 128) {
        int m = tid>>2, f3 = tid&3;
        float x = pos[((size_t)(row0+m)*16 + 0)*4 + f3];
        int q = (int)rintf(fminf(fmaxf(x*31.75f,-127.f),127.f));
        unsigned char qb = (unsigned char)q;
        abuf[0][m][512+f3]=qb; abuf[0][m][516+f3]=qb; abuf[0][m][520+f3]=qb; abuf[0][m][524+f3]=qb;
    }
    __syncthreads();

    // ---- pos encoder ----
    #pragma unroll 1
    for (int t=0;t<16;++t){
        int rb=t&1, wbuf=(t+1)&1;
        pass(rb,wbuf,wpp,0,cc0,gs1,0,0,dmy);
        pass(rb,wbuf,wpp,1,cc1,gs1,0,0,dmy);
        if (t<15 && tid<128){
            int m=tid>>2, f3=tid&3;
            float x = pos[((size_t)(row0+m)*16 + t+1)*4 + f3];
            int q = (int)rintf(fminf(fmaxf(x*31.75f,-127.f),127.f));
            unsigned char qb=(unsigned char)q;
            abuf[wbuf][m][512+f3]=qb; abuf[wbuf][m][516+f3]=qb; abuf[wbuf][m][520+f3]=qb; abuf[wbuf][m][524+f3]=qb;
        }
        __syncthreads();
    }
    // ---- combine: c += c_s; stage x=pos[:,15,:] into abuf[0]; h_p in abuf[0], h_s in hsave ----
    if (tid < 128) {
        int m = tid>>2, f3 = tid&3;
        float x = pos[((size_t)(row0+m)*16 + 15)*4 + f3];
        int q = (int)rintf(fminf(fmaxf(x*31.75f,-127.f),127.f));
        unsigned char qb = (unsigned char)q;
        abuf[0][m][512+f3]=qb; abuf[0][m][516+f3]=qb; abuf[0][m][520+f3]=qb; abuf[0][m][524+f3]=qb;
    }
    #pragma unroll
    for (int s2=0;s2<2;++s2)
        #pragma unroll
        for (int mf=0;mf<2;++mf)
            #pragma unroll
            for (int up=0;up<2;++up)
                #pragma unroll
                for (int r=0;r<4;++r){
                    int idx=(mf*2+up)*4+r;
                    float v = csave[mf*16+lq*4+r][(2*wv+s2)*32+up*16+l15];
                    if (s2) cc1[idx]+=v; else cc0[idx]+=v;
                }
    __syncthreads();

    // ---- decoder ----
    #pragma unroll 1
    for (int t=0;t<16;++t){
        int hb;
        if (t == 0) {
            // gates = Wd*(h_p) + Wd*(h_s) + Wd_ih*x + b via dual K-pass; defer h-writes
            int hq0[16], hq1[16];
            pass(0,0,wdp,0,cc0,gs2,1,1,hq0);
            pass(0,0,wdp,1,cc1,gs2,1,1,hq1);
            __syncthreads();
            #pragma unroll
            for (int s2=0;s2<2;++s2)
                #pragma unroll
                for (int mf=0;mf<2;++mf)
                    #pragma unroll
                    for (int up=0;up<2;++up)
                        #pragma unroll
                        for (int r=0;r<4;++r){
                            int idx=(mf*2+up)*4+r;
                            int q = s2 ? hq1[idx] : hq0[idx];
                            abuf[0][mf*16+lq*4+r][(2*wv+s2)*32+up*16+l15] = (unsigned char)q;
                        }
            hb = 0;
        } else {
            int rb=(t+1)&1, wbuf=t&1;
            pass(rb,wbuf,wdp,0,cc0,gs2,0,0,dmy);
            pass(rb,wbuf,wdp,1,cc1,gs2,0,0,dmy);
            hb = wbuf;
        }
        __syncthreads();
        {   // crossing partials: wave wv covers k-slice [wv*64, wv*64+64)
            int r = lane>>1, col = lane&1;
            const unsigned char* hp = &abuf[hb][r][wv*64];
            const float* wp = &smallw[col*512 + wv*64];
            float p = 0.f;
            #pragma unroll
            for (int k4=0;k4<16;++k4){
                int v = *(const int*)(hp + k4*4);
                p += (float)((signed char)(v    )) * wp[k4*4+0];
                p += (float)((signed char)(v>>8 )) * wp[k4*4+1];
                p += (float)((signed char)(v>>16)) * wp[k4*4+2];
                p += (float)((signed char)(v>>24)) * wp[k4*4+3];
            }
            partial[wv*64 + lane] = p;
        }
        __syncthreads();
        if (wv == 0) {
            float p = 0.f;
            #pragma unroll
            for (int i=0;i<8;++i) p += partial[i*64 + lane];
            int r = lane>>1, col = lane&1;
            p = p*(1.f/127.f) + smallw[1024+col];
            float cr = fmaxf(p, 0.f);
            float other = __shfl_xor(cr, 1, 64);
            float mx = fmaxf(cr, other);
            float e0 = ex2(LOG2E*(cr-mx)), e1 = ex2(LOG2E*(other-mx));
            out[((size_t)(row0+r))*32 + t*2 + col] = e0*rcpn(e0+e1);
            float c0v = col ? other : cr;
            float c1v = col ? cr : other;
            #pragma unroll
            for (int q2=0;q2<2;++q2){
                int e = col*2 + q2;
                float lp = fmaxf(c0v*smallw[1026+e*2] + c1v*smallw[1026+e*2+1] + smallw[1034+e], 0.f);
                int qv = (int)rintf(fminf(lp*31.75f, 127.f));
                unsigned char qb = (unsigned char)qv;
                abuf[hb][r][512+e]=qb; abuf[hb][r][516+e]=qb; abuf[hb][r][520+e]=qb; abuf[hb][r][524+e]=qb;
            }
        }
        __syncthreads();
    }
}

extern "C" void kernel_launch(void* const* d_in, const int* in_sizes, int n_in,
                              void* d_out, int out_size, void* d_ws, size_t ws_size,
                              hipStream_t stream)
{
    (void)in_sizes; (void)n_in; (void)out_size; (void)ws_size;
    const float* speed = (const float*)d_in[0];
    const float* pos   = (const float*)d_in[1];
    const float* Ws_ih = (const float*)d_in[2];
    const float* Ws_hh = (const float*)d_in[3];
    const float* bs_ih = (const float*)d_in[4];
    const float* bs_hh = (const float*)d_in[5];
    const float* Wp_ih = (const float*)d_in[6];
    const float* Wp_hh = (const float*)d_in[7];
    const float* bp_ih = (const float*)d_in[8];
    const float* bp_hh = (const float*)d_in[9];
    const float* Wd_ih = (const float*)d_in[10];
    const float* Wd_hh = (const float*)d_in[11];
    const float* bd_ih = (const float*)d_in[12];
    const float* bd_hh = (const float*)d_in[13];
    const float* W_fc  = (const float*)d_in[14];
    const float* b_fc  = (const float*)d_in[15];
    const float* W_emb = (const float*)d_in[16];
    const float* b_emb = (const float*)d_in[17];

    unsigned char* wp8 = (unsigned char*)d_ws;
    int*   smax  = (int*)(wp8 + 3*(size_t)LSTR);        // poisoned 0xAA.. = negative: atomicMax ok
    float* gsout = (float*)(wp8 + 3*(size_t)LSTR + 16);

    scale_k<<<96, 256, 0, stream>>>(Ws_ih,Ws_hh,bs_ih,bs_hh, Wp_ih,Wp_hh,bp_ih,bp_hh,
                                    Wd_ih,Wd_hh,bd_ih,bd_hh, smax);
    int gb = (LSTR/4 + 255) / 256;
    pack_k<<<gb, 256, 0, stream>>>(Ws_ih, Ws_hh, bs_ih, bs_hh, smax, 0, wp8,            gsout);
    pack_k<<<gb, 256, 0, stream>>>(Wp_ih, Wp_hh, bp_ih, bp_hh, smax, 1, wp8 +   (size_t)LSTR, gsout);
    pack_k<<<gb, 256, 0, stream>>>(Wd_ih, Wd_hh, bd_ih, bd_hh, smax, 2, wp8 + 2*(size_t)LSTR, gsout);
    lstm_all<<<NBLK, NTHR, 0, stream>>>(speed, pos, wp8, gsout,
                                        W_fc, b_fc, W_emb, b_emb, (float*)d_out);
}